// Round 6
// baseline (142.286 us; speedup 1.0000x reference)
//
#include <hip/hip_runtime.h>

// NEAT windowed-DAG forward, R12: scalar-pipe weight delivery, 1 element/lane.
//   values[0:16] = x; for i in 0..511: v = tanh(dot(values[i:i+16], w[i]) + b[i]) * r[i]
//   out = values[T-64:T]
//
// Cross-round model (R6-R11): wall = per-CU DS-pipe floor + ~44 cyc slip.
// Any scheme delivering weights via LDS pays an invariant ~8KB/node/CU
// (~10 b128 wave-instructions ~ 120 cyc/node); R9/R11 sit exactly at
// 120+44=164. Fix: weights are WAVE-UNIFORM -> deliver them through the
// idle scalar pipe (s_load -> SGPR; v_fma_f32 takes 1 SGPR operand).
// This forces 1 element/lane, which also deletes every cross-lane op:
// no DPP reduce, no migration, no masks. 22 VALU/node, ZERO DS traffic.
//
// SMEM returns OOO -> counted lgkmcnt unusable (R6), but depth-1 dbuf with
// lgkmcnt(0) is sound: wait(setP) / issue chunk+1 into setQ / compute setP.
// Each wait targets loads issued one 2-node chunk (~100-180cyc) earlier.
//
// A prep kernel packs transformed weights into d_ws (needs >= 36 KB):
// per 16-node supergroup (1088 B): 16x16 w" then 16x B".
//   w"[n][j] = -2*kScale*w[n][j]*rho_src,  B" = kScale*(b + sum_j w*rho).
// u-domain recurrence (R8-R11 verified): u = rcp(exp2(Sum w"u + B") + 1);
// inputs u=(1-x)/2; outputs o = rho*(1-2u).

typedef float sf16 __attribute__((ext_vector_type(16)));
typedef float sf2  __attribute__((ext_vector_type(2)));

constexpr int   kBatch  = 32768;
constexpr float kScale  = 2.8853900817779268f;   // 2*log2(e)
constexpr int   kSgF    = 272;                   // floats per supergroup record (1088 B)

// ---------------- prep: pack transformed weights into workspace ----------------
__global__ __launch_bounds__(64) void neat_prep(
    const float* __restrict__ w, const float* __restrict__ bias,
    const float* __restrict__ resp, float* __restrict__ pk)
{
    const int n = blockIdx.x * 64 + threadIdx.x;      // node 0..511
    const float4* w4 = reinterpret_cast<const float4*>(w) + n * 4;
    float4 a0 = w4[0], a1 = w4[1], a2 = w4[2], a3 = w4[3];
    const float m2k = -2.0f * kScale;
    float sum = 0.0f;
    float ws0,ws1,ws2,ws3,ws4,ws5,ws6,ws7,ws8,ws9,ws10,ws11,ws12,ws13,ws14,ws15;
    #define DO(J, V) { float rho = (n + (J) < 16) ? 1.0f : resp[n + (J) - 16]; \
                       float wr = (V) * rho; sum += wr; ws##J = wr * m2k; }
    DO(0,a0.x) DO(1,a0.y) DO(2,a0.z)  DO(3,a0.w)
    DO(4,a1.x) DO(5,a1.y) DO(6,a1.z)  DO(7,a1.w)
    DO(8,a2.x) DO(9,a2.y) DO(10,a2.z) DO(11,a2.w)
    DO(12,a3.x) DO(13,a3.y) DO(14,a3.z) DO(15,a3.w)
    #undef DO
    const float B = (bias[n] + sum) * kScale;
    const int sg = n >> 4, j = n & 15;
    float* gb = pk + sg * kSgF + j * 16;
    reinterpret_cast<float4*>(gb)[0] = make_float4(ws0,  ws1,  ws2,  ws3);
    reinterpret_cast<float4*>(gb)[1] = make_float4(ws4,  ws5,  ws6,  ws7);
    reinterpret_cast<float4*>(gb)[2] = make_float4(ws8,  ws9,  ws10, ws11);
    reinterpret_cast<float4*>(gb)[3] = make_float4(ws12, ws13, ws14, ws15);
    pk[sg * kSgF + 256 + j] = B;
}

// ---------------- main ----------------
// Chunk = 2 nodes = 2x s_load_dwordx16 (weights) + 1x s_load_dwordx2 (B"s).
// Supergroup offsets: chunk c weights at c*128 B, meta at 1024 + c*8 B.
#define SLOAD(S, BASEV, OFF)                                                  \
    asm volatile("s_load_dwordx16 %0, %3, %4\n\t"                             \
                 "s_load_dwordx16 %1, %3, %5\n\t"                             \
                 "s_load_dwordx2  %2, %3, %6"                                 \
      : "=s"(wA##S), "=s"(wB##S), "=s"(mm##S)                                 \
      : "s"(BASEV), "n"(OFF), "n"((OFF) + 64), "n"(1024 + ((OFF) >> 4)));

// lgkmcnt(0): only set S's loads are outstanding (issued one chunk ago).
// "+s" ties the consumers to this wait (proven R6-R11 pattern, s-class).
#define SWAIT(S)                                                              \
    asm volatile("s_waitcnt lgkmcnt(0)"                                       \
      : "+s"(wA##S), "+s"(wB##S), "+s"(mm##S));

// One node: 16 fma (SGPR weights) in 4 partials (dependent tap T15 is the
// LAST fma of p3 -> only serial-chain op), join tree, exp2, add, rcp.
#define NODE(W, BB, T0,T1,T2,T3,T4,T5,T6,T7,T8,T9,T10,T11,T12,T13,T14,T15, OUTR) { \
    float p0 = fmaf((T0), (W)[0], (BB));                                      \
    p0 = fmaf((T1), (W)[1], p0);                                              \
    p0 = fmaf((T2), (W)[2], p0);                                              \
    p0 = fmaf((T3), (W)[3], p0);                                              \
    float p1 = (T4) * (W)[4];                                                 \
    p1 = fmaf((T5), (W)[5], p1);                                              \
    p1 = fmaf((T6), (W)[6], p1);                                              \
    p1 = fmaf((T7), (W)[7], p1);                                              \
    float p2 = (T8) * (W)[8];                                                 \
    p2 = fmaf((T9),  (W)[9],  p2);                                            \
    p2 = fmaf((T10), (W)[10], p2);                                            \
    p2 = fmaf((T11), (W)[11], p2);                                            \
    float p3 = (T12) * (W)[12];                                               \
    p3 = fmaf((T13), (W)[13], p3);                                            \
    p3 = fmaf((T14), (W)[14], p3);                                            \
    p3 = fmaf((T15), (W)[15], p3);      /* T15 = u_{k-1}: chain starts */     \
    float sz = (p0 + p1) + (p2 + p3);                                         \
    float ez = __builtin_amdgcn_exp2f(sz);                                    \
    (OUTR) = __builtin_amdgcn_rcpf(ez + 1.0f); }

__global__ __launch_bounds__(64) void neat_fwd(
    const float* __restrict__ x,      // [B, 16]
    const float* __restrict__ resp,   // [512]
    const float* __restrict__ pk,     // packed weights (workspace)
    float* __restrict__ out)          // [B, 64]
{
    const int e = blockIdx.x * 64 + threadIdx.x;      // 1 element per lane

    // ---- window init: m_c = u-encoded x_c (u = (1-x)/2, exact affine) ----
    const float4* __restrict__ x4 = reinterpret_cast<const float4*>(x) + (size_t)e * 4;
    float4 X0 = x4[0], X1 = x4[1], X2 = x4[2], X3 = x4[3];
    float m0  = fmaf(-0.5f, X0.x, 0.5f), m1  = fmaf(-0.5f, X0.y, 0.5f);
    float m2  = fmaf(-0.5f, X0.z, 0.5f), m3  = fmaf(-0.5f, X0.w, 0.5f);
    float m4  = fmaf(-0.5f, X1.x, 0.5f), m5  = fmaf(-0.5f, X1.y, 0.5f);
    float m6  = fmaf(-0.5f, X1.z, 0.5f), m7  = fmaf(-0.5f, X1.w, 0.5f);
    float m8  = fmaf(-0.5f, X2.x, 0.5f), m9  = fmaf(-0.5f, X2.y, 0.5f);
    float m10 = fmaf(-0.5f, X2.z, 0.5f), m11 = fmaf(-0.5f, X2.w, 0.5f);
    float m12 = fmaf(-0.5f, X3.x, 0.5f), m13 = fmaf(-0.5f, X3.y, 0.5f);
    float m14 = fmaf(-0.5f, X3.z, 0.5f), m15 = fmaf(-0.5f, X3.w, 0.5f);

    float* __restrict__ op = out + (size_t)e * 64;
    const uint64_t pkb = (uint64_t)pk;

    sf16 wA0, wB0, wA1, wB1;
    sf2  mm0, mm1;

    SLOAD(0, pkb, 0)          // chunk 0 in flight

    #pragma unroll 1
    for (int g = 0; g < 32; ++g) {
        const uint64_t base  = pkb + (uint64_t)g * 1088u;
        const uint64_t base2 = base + 1088u;     // next supergroup (padded at g=31)

        SWAIT(0) SLOAD(1, base, 128)
        NODE(wA0, mm0[0], m0,m1,m2,m3,m4,m5,m6,m7,m8,m9,m10,m11,m12,m13,m14,m15, m0)
        NODE(wB0, mm0[1], m1,m2,m3,m4,m5,m6,m7,m8,m9,m10,m11,m12,m13,m14,m15,m0, m1)
        SWAIT(1) SLOAD(0, base, 256)
        NODE(wA1, mm1[0], m2,m3,m4,m5,m6,m7,m8,m9,m10,m11,m12,m13,m14,m15,m0,m1, m2)
        NODE(wB1, mm1[1], m3,m4,m5,m6,m7,m8,m9,m10,m11,m12,m13,m14,m15,m0,m1,m2, m3)
        SWAIT(0) SLOAD(1, base, 384)
        NODE(wA0, mm0[0], m4,m5,m6,m7,m8,m9,m10,m11,m12,m13,m14,m15,m0,m1,m2,m3, m4)
        NODE(wB0, mm0[1], m5,m6,m7,m8,m9,m10,m11,m12,m13,m14,m15,m0,m1,m2,m3,m4, m5)
        SWAIT(1) SLOAD(0, base, 512)
        NODE(wA1, mm1[0], m6,m7,m8,m9,m10,m11,m12,m13,m14,m15,m0,m1,m2,m3,m4,m5, m6)
        NODE(wB1, mm1[1], m7,m8,m9,m10,m11,m12,m13,m14,m15,m0,m1,m2,m3,m4,m5,m6, m7)
        SWAIT(0) SLOAD(1, base, 640)
        NODE(wA0, mm0[0], m8,m9,m10,m11,m12,m13,m14,m15,m0,m1,m2,m3,m4,m5,m6,m7, m8)
        NODE(wB0, mm0[1], m9,m10,m11,m12,m13,m14,m15,m0,m1,m2,m3,m4,m5,m6,m7,m8, m9)
        SWAIT(1) SLOAD(0, base, 768)
        NODE(wA1, mm1[0], m10,m11,m12,m13,m14,m15,m0,m1,m2,m3,m4,m5,m6,m7,m8,m9, m10)
        NODE(wB1, mm1[1], m11,m12,m13,m14,m15,m0,m1,m2,m3,m4,m5,m6,m7,m8,m9,m10, m11)
        SWAIT(0) SLOAD(1, base, 896)
        NODE(wA0, mm0[0], m12,m13,m14,m15,m0,m1,m2,m3,m4,m5,m6,m7,m8,m9,m10,m11, m12)
        NODE(wB0, mm0[1], m13,m14,m15,m0,m1,m2,m3,m4,m5,m6,m7,m8,m9,m10,m11,m12, m13)
        SWAIT(1) SLOAD(0, base2, 0)
        NODE(wA1, mm1[0], m14,m15,m0,m1,m2,m3,m4,m5,m6,m7,m8,m9,m10,m11,m12,m13, m14)
        NODE(wB1, mm1[1], m15,m0,m1,m2,m3,m4,m5,m6,m7,m8,m9,m10,m11,m12,m13,m14, m15)

        // After 16 nodes: m_c = u_{16g+c}. Decode/store output groups.
        if (g >= 28) {
            const int mq = g - 28;
            const float4* __restrict__ rr =
                reinterpret_cast<const float4*>(resp + 448 + 16 * mq);  // broadcast
            float4 R0 = rr[0], R1 = rr[1], R2 = rr[2], R3 = rr[3];
            float4* o4 = reinterpret_cast<float4*>(op + 16 * mq);
            o4[0] = make_float4(R0.x * fmaf(-2.0f, m0,  1.0f),
                                R0.y * fmaf(-2.0f, m1,  1.0f),
                                R0.z * fmaf(-2.0f, m2,  1.0f),
                                R0.w * fmaf(-2.0f, m3,  1.0f));
            o4[1] = make_float4(R1.x * fmaf(-2.0f, m4,  1.0f),
                                R1.y * fmaf(-2.0f, m5,  1.0f),
                                R1.z * fmaf(-2.0f, m6,  1.0f),
                                R1.w * fmaf(-2.0f, m7,  1.0f));
            o4[2] = make_float4(R2.x * fmaf(-2.0f, m8,  1.0f),
                                R2.y * fmaf(-2.0f, m9,  1.0f),
                                R2.z * fmaf(-2.0f, m10, 1.0f),
                                R2.w * fmaf(-2.0f, m11, 1.0f));
            o4[3] = make_float4(R3.x * fmaf(-2.0f, m12, 1.0f),
                                R3.y * fmaf(-2.0f, m13, 1.0f),
                                R3.z * fmaf(-2.0f, m14, 1.0f),
                                R3.w * fmaf(-2.0f, m15, 1.0f));
        }
    }

    // Drain the overrun prefetch (pad supergroup) before SGPR dealloc.
    asm volatile("s_waitcnt lgkmcnt(0)" ::: "memory");
}

extern "C" void kernel_launch(void* const* d_in, const int* in_sizes, int n_in,
                              void* d_out, int out_size, void* d_ws, size_t ws_size,
                              hipStream_t stream) {
    const float* x    = (const float*)d_in[0];
    const float* w    = (const float*)d_in[1];
    const float* bias = (const float*)d_in[2];
    const float* resp = (const float*)d_in[3];
    float* out = (float*)d_out;
    float* pk  = (float*)d_ws;        // needs 32 supergroups + 1 pad = 36 KB
    // in_sizes[4] (src_idx) encodes the fixed windowed topology; hardcoded above.
    hipLaunchKernelGGL(neat_prep, dim3(8),   dim3(64), 0, stream, w, bias, resp, pk);
    hipLaunchKernelGGL(neat_fwd,  dim3(512), dim3(64), 0, stream, x, resp, pk, out);
}

// Round 7
// 88.641 us; speedup vs baseline: 1.6052x; 1.6052x over previous
//
#include <hip/hip_runtime.h>

// NEAT windowed-DAG forward, R13: pair-split + f16 packed weights.
//   values[0:16] = x; for i in 0..511: v = tanh(dot(values[i:i+16], w[i]) + b[i]) * r[i]
//   out = values[T-64:T]
//
// Cross-round model (R6-R12): wall = LDS return-BW floor + occupancy slip.
// The floor is BYTES-to-VGPR and split-invariant: f32 weights = ~8.7KB/node/CU
// ~ 120 cyc; R9/R11 sit at 120+44=164 cyc/node. R10 (fewer waves) and R12
// (SMEM, K$-thrash) broke occupancy and lost to latency slip instead.
// Only remaining lever on the floor: bytes/weight. f16 RNE weights halve DS
// traffic (60 cyc/node/CU). Error analysis: u-domain identity is exact under
// weight perturbation; f16 delta ~ |w''| 2^-12 -> z'' err ~1e-4 rms, du ~2e-5,
// propagation gain < 1 -> final err << 2^-8 budget.
//
// Structure = R9 verbatim (proven): 1024 waves, 4/CU (1/SIMD on all SIMDs),
// lane j of a pair holds window positions 8j..8j+7; per node 8 fma (f16
// weights via (float) cast -> v_fma_mix or cvt+fma) + 1 dpp-add reduce +
// exp2+add+rcp + 1-reg migration. u-domain: u=sigmoid(-2z) carried; inputs
// u=(1-x)/2; outputs o=rho*(1-2u); B'' = kScale*(b+sum w*rho) in f32 meta.
//
// LDS delivery: per 2-node group (96 B): nodeA packed-f16 weights lane0-half
// [0,16)B lane1-half [16,32)B, nodeB at [32,64)B, meta f32 (B''A,B''B) rep0
// at [64,72)B rep1 at [80,88)B. Cursor a = base + 16*jl serves both lanes.
// 3 reads/group (2x b128 + 1x b64), 4 rotating sets, depth-3 prefetch,
// exact counted s_waitcnt lgkmcnt(9) (3 reads x 3 newer groups).

typedef float    v4f __attribute__((ext_vector_type(4)));
typedef float    v2f __attribute__((ext_vector_type(2)));
typedef _Float16 h8  __attribute__((ext_vector_type(8)));

constexpr int   kNOut     = 64;
constexpr int   kBatch    = 32768;
constexpr int   kGStrideF = 24;                      // floats per 2-node group (96 B)
constexpr int   kGStrideB = 96;
constexpr int   kLdsFloats = (256 + 3) * kGStrideF;  // 256 groups + prefetch overrun pad
constexpr float kScale    = 2.8853900817779268f;     // 2*log2(e)

// quad_perm DPP through the builtin so the compiler handles hazard nops.
#define QPERM(X, CTRL) __int_as_float(__builtin_amdgcn_update_dpp(            \
    __float_as_int(X), __float_as_int(X), (CTRL), 0xF, 0xF, false))

__device__ __forceinline__ unsigned pack2(float lo, float hi) {
    _Float16 l = (_Float16)lo, h = (_Float16)hi;    // RNE converts
    unsigned short ul = __builtin_bit_cast(unsigned short, l);
    unsigned short uh = __builtin_bit_cast(unsigned short, h);
    return ((unsigned)uh << 16) | ul;
}

// 3 ds_read for group S: nodeA weights (b128: lane j gets its 8 f16),
// nodeB weights, meta b64 (B''A, B''B) -- lane replica via cursor +16*jl.
#define PREF(S) {                                                             \
    asm volatile(                                                             \
      "ds_read_b128 %0, %3 offset:0\n\t"                                      \
      "ds_read_b128 %1, %3 offset:32\n\t"                                     \
      "ds_read_b64  %2, %3 offset:64"                                         \
      : "=&v"(qw0[S]), "=&v"(qw1[S]), "=&v"(qm[S])                            \
      : "v"(a));                                                              \
    a += kGStrideB; }

// After PREF of group G+3, the 9 newer reads (groups G+1..G+3) may remain
// outstanding; in-order DS returns make lgkmcnt(9) == "set G landed".
// "+v" ties the consumers to this asm (proven R6-R12 pattern).
#define WAITG(S)                                                              \
    asm volatile("s_waitcnt lgkmcnt(9)"                                       \
      : "+v"(qw0[S]), "+v"(qw1[S]), "+v"(qm[S]));

// One node. A0..A7 = lane's window half in age order (lane1's A7 = previous
// node's u -> consumed by the LAST fma, the only serial-chain op). BH = B''/2
// enters both lanes' fma init (pair reduce restores B''). Weights: 8 packed
// f16 in one b128; (float) cast folds into v_fma_mix_f32 (or cvt+fma).
// Migration: lane0's vacated A0 pulls lane1's A0; lane1's A0 gets new u.
#define NODE1(QW, BH, A0,A1,A2,A3,A4,A5,A6,A7) {                              \
    h8 wh = __builtin_bit_cast(h8, (QW));                                     \
    float p = fmaf((A0), (float)wh[0], (BH));                                 \
    p = fmaf((A1), (float)wh[1], p);                                          \
    p = fmaf((A2), (float)wh[2], p);                                          \
    p = fmaf((A3), (float)wh[3], p);                                          \
    p = fmaf((A4), (float)wh[4], p);                                          \
    p = fmaf((A5), (float)wh[5], p);                                          \
    p = fmaf((A6), (float)wh[6], p);                                          \
    p = fmaf((A7), (float)wh[7], p);                                          \
    float s_ = p + QPERM(p, 0xB1);          /* quad_perm:[1,0,3,2] */         \
    float mg = QPERM((A0), 0xB1);           /* pull partner's A0 */           \
    float ex = __builtin_amdgcn_exp2f(s_);                                    \
    float un = __builtin_amdgcn_rcpf(ex + 1.0f);                              \
    (A0) = is_l1 ? un : mg; }

// 2-node group: prefetch group G+3, wait for group G, run both nodes
// (second node's taps = first's rotated by one; A0 recycled as newest).
#define GROUP(G, A0,A1,A2,A3,A4,A5,A6,A7) {                                   \
    PREF(((G) + 3) & 3)                                                       \
    WAITG((G) & 3)                                                            \
    NODE1(qw0[(G) & 3], qm[(G) & 3].x, A0,A1,A2,A3,A4,A5,A6,A7)               \
    NODE1(qw1[(G) & 3], qm[(G) & 3].y, A1,A2,A3,A4,A5,A6,A7,A0) }

__global__ __launch_bounds__(256) void neat_fwd(
    const float* __restrict__ x,      // [B, 16]
    const float* __restrict__ w,      // [512, 16]
    const float* __restrict__ bias,   // [512]
    const float* __restrict__ resp,   // [512]
    float* __restrict__ out)          // [B, 64]
{
    __shared__ alignas(16) float ldsw[kLdsFloats];
    __shared__ float rst[512];

    const int t  = threadIdx.x;       // 0..255 (4 waves)
    const int jl = t & 1;             // lane within pair
    const bool is_l1 = (jl == 1);

    // ---- Stage: raw resp first ----
    rst[t] = resp[t];
    rst[t + 256] = resp[t + 256];
    __syncthreads();

    // ---- Stage per node (each thread owns 2 whole nodes): ----
    // w'' = -2*kScale*w*rho packed to f16 (RNE); B'' = kScale*(b+sum w*rho)/2
    // per-lane halves: lane0 = w''[0..7], lane1 = w''[8..15].
    const float4* __restrict__ w4 = reinterpret_cast<const float4*>(w);
    const float m2k = -2.0f * kScale;
    #pragma unroll
    for (int k = 0; k < 2; ++k) {
        int n = t + (k << 8);
        const float4* wn = w4 + n * 4;
        float4 a0 = wn[0], a1 = wn[1], a2 = wn[2], a3 = wn[3];
        float sum = 0.0f;
        float ws0,ws1,ws2,ws3,ws4,ws5,ws6,ws7,ws8,ws9,ws10,ws11,ws12,ws13,ws14,ws15;
        #define DO(J, V) { float rho = (n + (J) < 16) ? 1.0f : rst[n + (J) - 16]; \
                           float wr = (V) * rho; sum += wr; ws##J = wr * m2k; }
        DO(0,a0.x)  DO(1,a0.y)  DO(2,a0.z)  DO(3,a0.w)
        DO(4,a1.x)  DO(5,a1.y)  DO(6,a1.z)  DO(7,a1.w)
        DO(8,a2.x)  DO(9,a2.y)  DO(10,a2.z) DO(11,a2.w)
        DO(12,a3.x) DO(13,a3.y) DO(14,a3.z) DO(15,a3.w)
        #undef DO
        int q = n >> 1, h = n & 1;
        uint4 lo = make_uint4(pack2(ws0,ws1),  pack2(ws2,ws3),
                              pack2(ws4,ws5),  pack2(ws6,ws7));
        uint4 hi = make_uint4(pack2(ws8,ws9),  pack2(ws10,ws11),
                              pack2(ws12,ws13), pack2(ws14,ws15));
        uint4* dst = reinterpret_cast<uint4*>(&ldsw[q * kGStrideF + h * 8]);
        dst[0] = lo;           // lane0 half, bytes [h*32, h*32+16)
        dst[1] = hi;           // lane1 half, bytes [h*32+16, h*32+32)
        float Bh = (bias[n] + sum) * (kScale * 0.5f);
        ldsw[q * kGStrideF + 16 + h] = Bh;   // rep0 (byte 64)
        ldsw[q * kGStrideF + 20 + h] = Bh;   // rep1 (byte 80)
    }

    // ---- Per-thread state: window half (u-encoded) ----
    const int e = blockIdx.x * 128 + (t >> 1);     // batch element
    const float4* __restrict__ x4p = reinterpret_cast<const float4*>(x);
    const float4 xa = x4p[e * 4 + 2 * jl], xb = x4p[e * 4 + 2 * jl + 1];
    // u-encode inputs: u = (1 - x)/2  (exact affine; t = 1-2u recovers x)
    float r0 = fmaf(-0.5f, xa.x, 0.5f);
    float r1 = fmaf(-0.5f, xa.y, 0.5f);
    float r2 = fmaf(-0.5f, xa.z, 0.5f);
    float r3 = fmaf(-0.5f, xa.w, 0.5f);
    float r4 = fmaf(-0.5f, xb.x, 0.5f);
    float r5 = fmaf(-0.5f, xb.y, 0.5f);
    float r6 = fmaf(-0.5f, xb.z, 0.5f);
    float r7 = fmaf(-0.5f, xb.w, 0.5f);

    const float4* __restrict__ rr4 = reinterpret_cast<const float4*>(resp);
    float* __restrict__ op = out + (size_t)e * kNOut + jl * 8;

    __syncthreads();   // drains staging ds ops (compiler lgkmcnt(0))

    // DS byte cursor (+ lane's 16B half-offset folded in).
    unsigned int a = (unsigned int)(unsigned long long)(&ldsw[0])
                   + (unsigned int)(jl << 4);

    v4f qw0[4], qw1[4];
    v2f qm[4];
    PREF(0) PREF(1) PREF(2)     // groups 0,1,2 in flight

    #pragma unroll 1
    for (int g = 0; g < 32; ++g) {
        // 16 nodes = 8 groups; tap names advance 2 per group (period 8).
        GROUP(0, r0,r1,r2,r3,r4,r5,r6,r7)
        GROUP(1, r2,r3,r4,r5,r6,r7,r0,r1)
        GROUP(2, r4,r5,r6,r7,r0,r1,r2,r3)
        GROUP(3, r6,r7,r0,r1,r2,r3,r4,r5)
        GROUP(4, r0,r1,r2,r3,r4,r5,r6,r7)
        GROUP(5, r2,r3,r4,r5,r6,r7,r0,r1)
        GROUP(6, r4,r5,r6,r7,r0,r1,r2,r3)
        GROUP(7, r6,r7,r0,r1,r2,r3,r4,r5)
        // After 16 nodes: lane0 r_c = u_{16g+c}, lane1 r_c = u_{16g+8+c}.
        if (g >= 28) {
            int m = g - 28;
            const float4 ra = rr4[112 + 4 * m + 2 * jl];
            const float4 rb = rr4[112 + 4 * m + 2 * jl + 1];
            float4 o0 = make_float4(fmaf(-2.0f, r0, 1.0f) * ra.x,
                                    fmaf(-2.0f, r1, 1.0f) * ra.y,
                                    fmaf(-2.0f, r2, 1.0f) * ra.z,
                                    fmaf(-2.0f, r3, 1.0f) * ra.w);
            float4 o1 = make_float4(fmaf(-2.0f, r4, 1.0f) * rb.x,
                                    fmaf(-2.0f, r5, 1.0f) * rb.y,
                                    fmaf(-2.0f, r6, 1.0f) * rb.z,
                                    fmaf(-2.0f, r7, 1.0f) * rb.w);
            *reinterpret_cast<float4*>(op + 16 * m)     = o0;
            *reinterpret_cast<float4*>(op + 16 * m + 4) = o1;
        }
    }

    // Drain overrun prefetches (pad groups 256..258).
    asm volatile("s_waitcnt lgkmcnt(0)" ::: "memory");
}

extern "C" void kernel_launch(void* const* d_in, const int* in_sizes, int n_in,
                              void* d_out, int out_size, void* d_ws, size_t ws_size,
                              hipStream_t stream) {
    const float* x    = (const float*)d_in[0];
    const float* w    = (const float*)d_in[1];
    const float* bias = (const float*)d_in[2];
    const float* resp = (const float*)d_in[3];
    float* out = (float*)d_out;
    // in_sizes[4] (src_idx) encodes the fixed windowed topology; hardcoded above.
    dim3 block(256);
    dim3 grid(kBatch / 128);   // 256 blocks -> 1/CU, 4 waves/CU = 1 per SIMD
    hipLaunchKernelGGL(neat_fwd, grid, block, 0, stream, x, w, bias, resp, out);
}

// Round 8
// 86.229 us; speedup vs baseline: 1.6501x; 1.0280x over previous
//
#include <hip/hip_runtime.h>

// NEAT windowed-DAG forward, R14: 8-node fence regions + injection chain + f16 weights.
//   values[0:16] = x; for i in 0..511: v = tanh(dot(values[i:i+16], w[i]) + b[i]) * r[i]
//   out = values[T-64:T]
//
// Model after R6-R13 (fits all 8 rounds): wall = serial chain (2 trans ops
// ~35-40cyc dep latency = ~88 cyc/node) + per-GROUP volatile-asm fence
// overhead, un-overlapped at 1 wave/SIMD. R9/R11/R13 all = 164 cyc/node
// because the PREF/WAIT fences every 2 nodes stop the scheduler from
// hoisting group G+1's off-chain fmas into group G's trans bubbles.
// Fix: ONE fence pair per 8 nodes (12 ds_read_b128, depth-1 dbuf, counted
// lgkmcnt(12)) -> compiler schedules ~130 instrs across 8 chains freely.
//
// Numerics = R11 (injection, verified) + R13 (f16 weights, verified):
//  * u-domain: u = sigmoid(-2z) carried; in u=(1-x)/2; out o = rho*(1-2u).
//  * delayed insert: lane1's newest tap is u_{k-2}; u_{k-1} enters only via
//    post-reduce inject fma(UIN, W15, s) -> chain = fma->exp2->add->rcp.
//  * lane0 taps u_{k-16+m} w/ w"[0..7]; lane1 taps u_{k-9+m} w/ [0,w8..w14]
//    (pad ZERO weight on lane1's oldest tap); meta (Bh, w15) f32.
//  * migration off-chain: A0 <- lane0: partner's A1 (u_{k-8}); lane1: u_{k-1}.
//
// Supergroup record (8 nodes, 384 B): node s weights at s*32 (+16*jl lane
// half, 8 packed f16); meta chunks m=0..3 at 256+m*32 (+16*jl replica):
// b128 = (Bh_{2m}, w15_{2m}, Bh_{2m+1}, w15_{2m+1}).

typedef float    v4f __attribute__((ext_vector_type(4)));
typedef _Float16 h8  __attribute__((ext_vector_type(8)));

constexpr int   kNOut   = 64;
constexpr int   kBatch  = 32768;
constexpr int   kSgF    = 96;                     // floats per supergroup (384 B)
constexpr int   kSgB    = 384;
constexpr int   kLdsFloats = 65 * kSgF;           // 64 supergroups + 1 pad (overrun)
constexpr float kScale  = 2.8853900817779268f;    // 2*log2(e)

// quad_perm DPP through the builtin so the compiler handles hazard nops.
#define QPERM(X, CTRL) __int_as_float(__builtin_amdgcn_update_dpp(            \
    __float_as_int(X), __float_as_int(X), (CTRL), 0xF, 0xF, false))

__device__ __forceinline__ unsigned pack2(float lo, float hi) {
    _Float16 l = (_Float16)lo, h = (_Float16)hi;    // RNE converts
    unsigned short ul = __builtin_bit_cast(unsigned short, l);
    unsigned short uh = __builtin_bit_cast(unsigned short, h);
    return ((unsigned)uh << 16) | ul;
}

// 12 ds_read_b128 for supergroup set S (8 weight + 4 meta); cursor a has
// the lane's +16B half-offset folded in. All lane-pairs read the same two
// addresses -> LDS broadcast, conflict-free.
#define PREF(S) {                                                             \
    asm volatile(                                                             \
      "ds_read_b128 %0, %12 offset:0\n\t"                                     \
      "ds_read_b128 %1, %12 offset:32\n\t"                                    \
      "ds_read_b128 %2, %12 offset:64\n\t"                                    \
      "ds_read_b128 %3, %12 offset:96\n\t"                                    \
      "ds_read_b128 %4, %12 offset:128\n\t"                                   \
      "ds_read_b128 %5, %12 offset:160\n\t"                                   \
      "ds_read_b128 %6, %12 offset:192\n\t"                                   \
      "ds_read_b128 %7, %12 offset:224\n\t"                                   \
      "ds_read_b128 %8, %12 offset:256\n\t"                                   \
      "ds_read_b128 %9, %12 offset:288\n\t"                                   \
      "ds_read_b128 %10, %12 offset:320\n\t"                                  \
      "ds_read_b128 %11, %12 offset:352"                                      \
      : "=&v"(qw0[S]), "=&v"(qw1[S]), "=&v"(qw2[S]), "=&v"(qw3[S]),           \
        "=&v"(qw4[S]), "=&v"(qw5[S]), "=&v"(qw6[S]), "=&v"(qw7[S]),           \
        "=&v"(qm0[S]), "=&v"(qm1[S]), "=&v"(qm2[S]), "=&v"(qm3[S])            \
      : "v"(a));                                                              \
    a += kSgB; }

// Depth-1 dbuf: when waiting for set S, only the other set's 12 reads are
// newer; in-order DS returns make lgkmcnt(12) == "set S landed". "+v" ties
// the consumers to this asm (proven R6-R13 pattern).
#define WAITR(S)                                                              \
    asm volatile("s_waitcnt lgkmcnt(12)"                                      \
      : "+v"(qw0[S]), "+v"(qw1[S]), "+v"(qw2[S]), "+v"(qw3[S]),               \
        "+v"(qw4[S]), "+v"(qw5[S]), "+v"(qw6[S]), "+v"(qw7[S]),               \
        "+v"(qm0[S]), "+v"(qm1[S]), "+v"(qm2[S]), "+v"(qm3[S]));

// One node (R11 semantics, f16 weights). All 8 partial fmas + pair reduce
// OFF-chain (no tap holds u_{k-1}; lane1's A0 pad weight is 0).
// Chain: acc = fma(UIN, W15, s) -> exp2 -> add -> rcp -> UOUT.
#define NODE1(QW, BH, W15, UIN, UOUT, A0,A1,A2,A3,A4,A5,A6,A7) {              \
    h8 wh = __builtin_bit_cast(h8, (QW));                                     \
    float p = fmaf((A0), (float)wh[0], (BH));                                 \
    p = fmaf((A1), (float)wh[1], p);                                          \
    p = fmaf((A2), (float)wh[2], p);                                          \
    p = fmaf((A3), (float)wh[3], p);                                          \
    p = fmaf((A4), (float)wh[4], p);                                          \
    p = fmaf((A5), (float)wh[5], p);                                          \
    p = fmaf((A6), (float)wh[6], p);                                          \
    p = fmaf((A7), (float)wh[7], p);                                          \
    float s_ = p + QPERM(p, 0xB1);          /* quad_perm:[1,0,3,2] */         \
    float mg = QPERM((A1), 0xB1);           /* partner's u_{k-8} */           \
    float acc = fmaf((UIN), (W15), s_);     /* chain starts here */           \
    float exv = __builtin_amdgcn_exp2f(acc);                                  \
    (UOUT) = __builtin_amdgcn_rcpf(exv + 1.0f);                               \
    (A0) = is_l1 ? (UIN) : mg; }

// 8-node region: one prefetch (other set), one counted wait, 8 nodes with
// tap names rotating left (period 8 -> names realign each region).
#define REGION(SP, SC) {                                                      \
    PREF(SP)                                                                  \
    WAITR(SC)                                                                 \
    NODE1(qw0[SC], qm0[SC].x, qm0[SC].y, u0, u1, r0,r1,r2,r3,r4,r5,r6,r7)     \
    NODE1(qw1[SC], qm0[SC].z, qm0[SC].w, u1, u0, r1,r2,r3,r4,r5,r6,r7,r0)     \
    NODE1(qw2[SC], qm1[SC].x, qm1[SC].y, u0, u1, r2,r3,r4,r5,r6,r7,r0,r1)     \
    NODE1(qw3[SC], qm1[SC].z, qm1[SC].w, u1, u0, r3,r4,r5,r6,r7,r0,r1,r2)     \
    NODE1(qw4[SC], qm2[SC].x, qm2[SC].y, u0, u1, r4,r5,r6,r7,r0,r1,r2,r3)     \
    NODE1(qw5[SC], qm2[SC].z, qm2[SC].w, u1, u0, r5,r6,r7,r0,r1,r2,r3,r4)     \
    NODE1(qw6[SC], qm3[SC].x, qm3[SC].y, u0, u1, r6,r7,r0,r1,r2,r3,r4,r5)     \
    NODE1(qw7[SC], qm3[SC].z, qm3[SC].w, u1, u0, r7,r0,r1,r2,r3,r4,r5,r6) }

__global__ __launch_bounds__(256) void neat_fwd(
    const float* __restrict__ x,      // [B, 16]
    const float* __restrict__ w,      // [512, 16]
    const float* __restrict__ bias,   // [512]
    const float* __restrict__ resp,   // [512]
    float* __restrict__ out)          // [B, 64]
{
    __shared__ alignas(16) float ldsw[kLdsFloats];
    __shared__ float rst[512];

    const int t  = threadIdx.x;       // 0..255 (4 waves)
    const int jl = t & 1;             // lane within pair
    const bool is_l1 = (jl == 1);

    // ---- Stage: raw resp first ----
    rst[t] = resp[t];
    rst[t + 256] = resp[t + 256];
    __syncthreads();

    // ---- Stage per node (each thread owns 2 whole nodes) ----
    // w" = -2*kScale*w*rho (f16 RNE); Bh = kScale*(b + sum_j w*rho)/2 (f32);
    // lane0 half [w"0..w"7]; lane1 half [0, w"8..w"14]; meta (Bh, w"15 f32).
    const float4* __restrict__ w4 = reinterpret_cast<const float4*>(w);
    const float m2k = -2.0f * kScale;
    #pragma unroll
    for (int k = 0; k < 2; ++k) {
        int n = t + (k << 8);
        const float4* wn = w4 + n * 4;
        float4 a0 = wn[0], a1 = wn[1], a2 = wn[2], a3 = wn[3];
        float sum = 0.0f;
        float ws0,ws1,ws2,ws3,ws4,ws5,ws6,ws7,ws8,ws9,ws10,ws11,ws12,ws13,ws14,ws15;
        #define DO(J, V) { float rho = (n + (J) < 16) ? 1.0f : rst[n + (J) - 16]; \
                           float wr = (V) * rho; sum += wr; ws##J = wr * m2k; }
        DO(0,a0.x)  DO(1,a0.y)  DO(2,a0.z)  DO(3,a0.w)
        DO(4,a1.x)  DO(5,a1.y)  DO(6,a1.z)  DO(7,a1.w)
        DO(8,a2.x)  DO(9,a2.y)  DO(10,a2.z) DO(11,a2.w)
        DO(12,a3.x) DO(13,a3.y) DO(14,a3.z) DO(15,a3.w)
        #undef DO
        const int sg = n >> 3, s = n & 7;
        float* gb = ldsw + sg * kSgF;
        // weights: lane0 half at byte s*32, lane1 half at +16
        uint4 lo = make_uint4(pack2(ws0, ws1),  pack2(ws2, ws3),
                              pack2(ws4, ws5),  pack2(ws6, ws7));
        uint4 hi = make_uint4(pack2(0.0f, ws8), pack2(ws9, ws10),
                              pack2(ws11,ws12), pack2(ws13,ws14));
        uint4* dst = reinterpret_cast<uint4*>(gb + s * 8);
        dst[0] = lo;
        dst[1] = hi;
        // meta chunk m = s>>1: (Bh,w15) pairs; lane0 at 256+m*32, lane1 +16
        float Bh = (bias[n] + sum) * (kScale * 0.5f);
        int mi = 64 + (s >> 1) * 8 + (s & 1) * 2;   // float index (lane0)
        gb[mi]     = Bh;  gb[mi + 1] = ws15;
        gb[mi + 4] = Bh;  gb[mi + 5] = ws15;        // lane1 replica (+16 B)
    }

    // ---- Per-thread window init (u-encoded inputs), R11 verbatim ----
    // Node 0 taps: lane0 = enc(x0..x7), lane1 = enc(x7..x14); u_prev = enc(x15).
    const int e = blockIdx.x * 128 + (t >> 1);     // batch element
    const float4* __restrict__ x4p = reinterpret_cast<const float4*>(x);
    float4 X0 = x4p[e*4+0], X1 = x4p[e*4+1], X2 = x4p[e*4+2], X3 = x4p[e*4+3];
    float xx0 = fmaf(-0.5f, X0.x, 0.5f), xx1 = fmaf(-0.5f, X0.y, 0.5f);
    float xx2 = fmaf(-0.5f, X0.z, 0.5f), xx3 = fmaf(-0.5f, X0.w, 0.5f);
    float xx4 = fmaf(-0.5f, X1.x, 0.5f), xx5 = fmaf(-0.5f, X1.y, 0.5f);
    float xx6 = fmaf(-0.5f, X1.z, 0.5f), xx7 = fmaf(-0.5f, X1.w, 0.5f);
    float xx8 = fmaf(-0.5f, X2.x, 0.5f), xx9 = fmaf(-0.5f, X2.y, 0.5f);
    float xx10 = fmaf(-0.5f, X2.z, 0.5f), xx11 = fmaf(-0.5f, X2.w, 0.5f);
    float xx12 = fmaf(-0.5f, X3.x, 0.5f), xx13 = fmaf(-0.5f, X3.y, 0.5f);
    float xx14 = fmaf(-0.5f, X3.z, 0.5f), xx15 = fmaf(-0.5f, X3.w, 0.5f);
    float r0 = is_l1 ? xx7  : xx0;
    float r1 = is_l1 ? xx8  : xx1;
    float r2 = is_l1 ? xx9  : xx2;
    float r3 = is_l1 ? xx10 : xx3;
    float r4 = is_l1 ? xx11 : xx4;
    float r5 = is_l1 ? xx12 : xx5;
    float r6 = is_l1 ? xx13 : xx6;
    float r7 = is_l1 ? xx14 : xx7;
    float u0 = xx15;          // u_{-1} (uniform)
    float u1 = 0.0f;

    const float4* __restrict__ rr4 = reinterpret_cast<const float4*>(resp);
    float* __restrict__ op = out + (size_t)e * kNOut + jl * 8;

    __syncthreads();   // drains staging ds ops (compiler lgkmcnt(0))

    // DS byte cursor (+ lane's 16B half-offset folded in).
    unsigned int a = (unsigned int)(unsigned long long)(&ldsw[0])
                   + (unsigned int)(jl << 4);

    v4f qw0[2], qw1[2], qw2[2], qw3[2], qw4[2], qw5[2], qw6[2], qw7[2];
    v4f qm0[2], qm1[2], qm2[2], qm3[2];
    PREF(0)                       // supergroup 0 in flight

    #pragma unroll 1
    for (int g = 0; g < 32; ++g) {
        REGION(1, 0)              // prefetch next 8 nodes, compute current 8
        REGION(0, 1)
        // After 16 nodes (R11 mapping): lane0 r_c = u_{16g+c};
        // lane1 r_{c+1} = u_{16g+8+c}; u_{16g+15} = u0.
        if (g >= 28) {
            int m = g - 28;
            const float4 ra = rr4[112 + 4 * m + 2 * jl];
            const float4 rb = rr4[112 + 4 * m + 2 * jl + 1];
            float o0 = is_l1 ? r1 : r0;
            float o1 = is_l1 ? r2 : r1;
            float o2 = is_l1 ? r3 : r2;
            float o3 = is_l1 ? r4 : r3;
            float o4 = is_l1 ? r5 : r4;
            float o5 = is_l1 ? r6 : r5;
            float o6 = is_l1 ? r7 : r6;
            float o7 = is_l1 ? u0 : r7;
            float4 q0_ = make_float4(fmaf(-2.0f, o0, 1.0f) * ra.x,
                                     fmaf(-2.0f, o1, 1.0f) * ra.y,
                                     fmaf(-2.0f, o2, 1.0f) * ra.z,
                                     fmaf(-2.0f, o3, 1.0f) * ra.w);
            float4 q1_ = make_float4(fmaf(-2.0f, o4, 1.0f) * rb.x,
                                     fmaf(-2.0f, o5, 1.0f) * rb.y,
                                     fmaf(-2.0f, o6, 1.0f) * rb.z,
                                     fmaf(-2.0f, o7, 1.0f) * rb.w);
            *reinterpret_cast<float4*>(op + 16 * m)     = q0_;
            *reinterpret_cast<float4*>(op + 16 * m + 4) = q1_;
        }
    }

    // Drain the overrun prefetch (pad supergroup 64).
    asm volatile("s_waitcnt lgkmcnt(0)" ::: "memory");
}

extern "C" void kernel_launch(void* const* d_in, const int* in_sizes, int n_in,
                              void* d_out, int out_size, void* d_ws, size_t ws_size,
                              hipStream_t stream) {
    const float* x    = (const float*)d_in[0];
    const float* w    = (const float*)d_in[1];
    const float* bias = (const float*)d_in[2];
    const float* resp = (const float*)d_in[3];
    float* out = (float*)d_out;
    // in_sizes[4] (src_idx) encodes the fixed windowed topology; hardcoded above.
    dim3 block(256);
    dim3 grid(kBatch / 128);   // 256 blocks -> 1/CU, 4 waves/CU = 1 per SIMD
    hipLaunchKernelGGL(neat_fwd, grid, block, 0, stream, x, w, bias, resp, out);
}